// Round 1
// baseline (2810.473 us; speedup 1.0000x reference)
//
#include <hip/hip_runtime.h>
#include <hip/hip_bf16.h>
#include <math.h>

#define D_MODEL 2048
#define VOCAB   32000
#define NTOK    8192
#define BM      128
#define BN      128
#define BK      32
#define LDK     (BK + 8)          // +8 bf16 pad -> 2-way-max LDS conflicts, keeps 16B align
#define MTILES  (NTOK / BM)       // 64
#define NTILES  (VOCAB / BN)      // 250
#define NCHUNK  (VOCAB / 64)      // 500 (each wave covers 64 cols)

typedef __attribute__((ext_vector_type(8))) short  frag8;   // 8 x bf16 (4 VGPRs)
typedef __attribute__((ext_vector_type(4))) float  f32x4;

// pack two fp32 -> two bf16 (truncation) in one v_perm_b32
__device__ inline unsigned pack_bf16(float x, float y) {
    union { float f; unsigned u; } a, b;
    a.f = x; b.f = y;
    // dest byte0,1 = x bytes 2,3 (src1); dest byte2,3 = y bytes 2,3 (src0)
    return __builtin_amdgcn_perm(b.u, a.u, 0x07060302u);
}

__global__ __launch_bounds__(256, 2)
void gemm_lse_kernel(const float* __restrict__ H, const float* __restrict__ W,
                     float* __restrict__ partials) {
    __shared__ unsigned short As[BM][LDK];
    __shared__ unsigned short Bs[BN][LDK];

    // supertile swizzle: 8 m-tiles share each n-block for L2 reuse
    const int GM = 8;
    int bid   = blockIdx.x;
    int super = bid / (GM * NTILES);
    int rem   = bid % (GM * NTILES);
    int mtile = super * GM + (rem % GM);
    int ntile = rem / GM;

    const int m0 = mtile * BM;
    const int n0 = ntile * BN;

    const int tid  = threadIdx.x;
    const int lane = tid & 63;
    const int w    = tid >> 6;          // wave 0..3
    const int wm   = (w >> 1) * 64;     // wave row offset in tile
    const int wn   = (w & 1)  * 64;     // wave col offset in tile
    const int q    = lane >> 4;         // 0..3
    const int c    = lane & 15;         // 0..15

    f32x4 acc[4][4];
    const f32x4 zero = {0.f, 0.f, 0.f, 0.f};
    #pragma unroll
    for (int i = 0; i < 4; ++i)
        #pragma unroll
        for (int j = 0; j < 4; ++j) acc[i][j] = zero;

    for (int kt = 0; kt < D_MODEL / BK; ++kt) {
        const int k0 = kt * BK;
        // stage 128x32 fp32 of A and B -> bf16 LDS (each thread: 4 float4 per matrix)
        #pragma unroll
        for (int s = 0; s < 4; ++s) {
            int i   = tid + s * 256;      // 0..1023
            int row = i >> 3;             // 8 float4 per row
            int kq  = (i & 7) << 2;       // float offset in row

            const float4* pa = (const float4*)(H + (size_t)(m0 + row) * D_MODEL + k0 + kq);
            float4 va = *pa;
            uint2 ba = { pack_bf16(va.x, va.y), pack_bf16(va.z, va.w) };
            *(uint2*)&As[row][kq] = ba;

            const float4* pb = (const float4*)(W + (size_t)(n0 + row) * D_MODEL + k0 + kq);
            float4 vb = *pb;
            uint2 bb = { pack_bf16(vb.x, vb.y), pack_bf16(vb.z, vb.w) };
            *(uint2*)&Bs[row][kq] = bb;
        }
        __syncthreads();

        frag8 af[4], bf[4];
        #pragma unroll
        for (int t = 0; t < 4; ++t)
            af[t] = *(const frag8*)&As[wm + t * 16 + c][q * 8];
        #pragma unroll
        for (int t = 0; t < 4; ++t)
            bf[t] = *(const frag8*)&Bs[wn + t * 16 + c][q * 8];

        #pragma unroll
        for (int tm = 0; tm < 4; ++tm)
            #pragma unroll
            for (int tn = 0; tn < 4; ++tn)
                acc[tm][tn] = __builtin_amdgcn_mfma_f32_16x16x32_bf16(
                    af[tm], bf[tn], acc[tm][tn], 0, 0, 0);
        __syncthreads();
    }

    // epilogue: per-row max & sum(exp) over this wave's 64 columns
    // C/D layout (m89/m91): col = lane&15, row = (lane>>4)*4 + reg
    const int chunk = ntile * 2 + (w & 1);
    #pragma unroll
    for (int tm = 0; tm < 4; ++tm) {
        #pragma unroll
        for (int r = 0; r < 4; ++r) {
            float v0 = acc[tm][0][r], v1 = acc[tm][1][r];
            float v2 = acc[tm][2][r], v3 = acc[tm][3][r];
            float mx = fmaxf(fmaxf(v0, v1), fmaxf(v2, v3));
            #pragma unroll
            for (int mask = 1; mask <= 8; mask <<= 1)
                mx = fmaxf(mx, __shfl_xor(mx, mask, 64));
            float sm = __expf(v0 - mx) + __expf(v1 - mx)
                     + __expf(v2 - mx) + __expf(v3 - mx);
            #pragma unroll
            for (int mask = 1; mask <= 8; mask <<= 1)
                sm += __shfl_xor(sm, mask, 64);
            if (c == 0) {
                int row_g = m0 + wm + tm * 16 + q * 4 + r;
                float* p = partials + ((size_t)row_g * NCHUNK + chunk) * 2;
                p[0] = mx;
                p[1] = sm;
            }
        }
    }
}

// exact fp32 dot(h[n], w[target[n]]); also zeroes the accumulators (block 0)
__global__ void tgt_kernel(const float* __restrict__ H, const float* __restrict__ W,
                           const int* __restrict__ targets,
                           float* __restrict__ tgt_logit, float* __restrict__ accum) {
    int token = blockIdx.x;
    int tid   = threadIdx.x;
    if (token == 0 && tid == 0) { accum[0] = 0.f; accum[1] = 0.f; }

    int t  = targets[token];
    int tt = (t == -100) ? 0 : t;
    const float4* h  = (const float4*)(H + (size_t)token * D_MODEL);
    const float4* wr = (const float4*)(W + (size_t)tt * D_MODEL);
    float p = 0.f;
    for (int j = tid; j < D_MODEL / 4; j += 256) {
        float4 a = h[j], b = wr[j];
        p += a.x * b.x + a.y * b.y + a.z * b.z + a.w * b.w;
    }
    #pragma unroll
    for (int mask = 1; mask < 64; mask <<= 1)
        p += __shfl_xor(p, mask, 64);

    __shared__ float lp[4];
    int lane = tid & 63, wid = tid >> 6;
    if (lane == 0) lp[wid] = p;
    __syncthreads();
    if (tid == 0) tgt_logit[token] = lp[0] + lp[1] + lp[2] + lp[3];
}

__device__ inline void lse_merge(float& m, float& s, float om, float os) {
    if (om > m) { s = s * __expf(m - om) + os; m = om; }
    else        { s += os * __expf(om - m); }
}

__global__ void reduce_kernel(const float* __restrict__ partials,
                              const float* __restrict__ tgt_logit,
                              const int* __restrict__ targets,
                              float* __restrict__ accum) {
    int token = blockIdx.x;
    int tid   = threadIdx.x;
    float m = -INFINITY, s = 0.f;
    for (int ch = tid; ch < NCHUNK; ch += 256) {
        const float* p = partials + ((size_t)token * NCHUNK + ch) * 2;
        lse_merge(m, s, p[0], p[1]);
    }
    #pragma unroll
    for (int mask = 1; mask < 64; mask <<= 1) {
        float om = __shfl_xor(m, mask, 64);
        float os = __shfl_xor(s, mask, 64);
        lse_merge(m, s, om, os);
    }
    __shared__ float lm[4], ls[4];
    int lane = tid & 63, wid = tid >> 6;
    if (lane == 0) { lm[wid] = m; ls[wid] = s; }
    __syncthreads();
    if (tid == 0) {
        for (int i = 1; i < 4; ++i) lse_merge(m, s, lm[i], ls[i]);
        float lse = m + __logf(s);
        int t = targets[token];
        if (t != -100) {
            atomicAdd(&accum[0], lse - tgt_logit[token]);
            atomicAdd(&accum[1], 1.0f);
        }
    }
}

__global__ void final_kernel(const float* __restrict__ accum, float* __restrict__ out) {
    float L = accum[0], C = accum[1];
    out[0] = (C > 0.f) ? (L / C) : 0.f;
}

extern "C" void kernel_launch(void* const* d_in, const int* in_sizes, int n_in,
                              void* d_out, int out_size, void* d_ws, size_t ws_size,
                              hipStream_t stream) {
    (void)in_sizes; (void)n_in; (void)out_size; (void)ws_size;
    const float* H       = (const float*)d_in[0];   // outputs [4,2048,2048]
    const int*   targets = (const int*)d_in[1];     // [8192]
    const float* W       = (const float*)d_in[2];   // [32000,2048]
    float*       out     = (float*)d_out;

    char*  ws        = (char*)d_ws;
    float* partials  = (float*)ws;                                   // 8192*500*2 f32 = 32 MB
    float* tgt_logit = (float*)(ws + (size_t)NTOK * NCHUNK * 2 * 4); // 8192 f32
    float* accum     = tgt_logit + NTOK;                             // 2 f32

    gemm_lse_kernel<<<MTILES * NTILES, 256, 0, stream>>>(H, W, partials);
    tgt_kernel<<<NTOK, 256, 0, stream>>>(H, W, targets, tgt_logit, accum);
    reduce_kernel<<<NTOK, 256, 0, stream>>>(partials, tgt_logit, targets, accum);
    final_kernel<<<1, 1, 0, stream>>>(accum, out);
}

// Round 2
// 1863.635 us; speedup vs baseline: 1.5081x; 1.5081x over previous
//
#include <hip/hip_runtime.h>
#include <hip/hip_bf16.h>
#include <math.h>

#define D_MODEL 2048
#define VOCAB   32000
#define NTOK    8192
#define BM      128
#define BN      128
#define BK      32
#define LDK     (BK + 8)          // fallback path only
#define MTILES  (NTOK / BM)       // 64
#define NTILES  (VOCAB / BN)      // 250
#define NCHUNK  (VOCAB / 64)      // 500

typedef __attribute__((ext_vector_type(8))) short  frag8;   // 8 x bf16 (4 VGPRs)
typedef __attribute__((ext_vector_type(4))) float  f32x4;

// ---------------- helpers ----------------

// async 16B/lane global->LDS (dest = wave-uniform base + lane*16)
__device__ inline void g2l16(const void* g, void* l) {
    __builtin_amdgcn_global_load_lds(
        (const __attribute__((address_space(1))) unsigned int*)g,
        (__attribute__((address_space(3))) unsigned int*)l,
        16, 0, 0);
}

__device__ inline unsigned short rne_bf16(float f) {
    union { float f; unsigned u; } x; x.f = f;
    unsigned r = x.u + 0x7FFFu + ((x.u >> 16) & 1u);
    return (unsigned short)(r >> 16);
}

// pack two fp32 -> two bf16 (truncation) in one v_perm_b32 (fallback path)
__device__ inline unsigned pack_bf16(float x, float y) {
    union { float f; unsigned u; } a, b;
    a.f = x; b.f = y;
    return __builtin_amdgcn_perm(b.u, a.u, 0x07060302u);
}

// ---------------- fp32 -> bf16 conversion pass ----------------

__global__ void cvt_bf16_kernel(const float* __restrict__ src, unsigned short* __restrict__ dst) {
    size_t i = (size_t)blockIdx.x * 256 + threadIdx.x;
    float4 v = ((const float4*)src)[i];
    ushort4 o;
    o.x = rne_bf16(v.x); o.y = rne_bf16(v.y); o.z = rne_bf16(v.z); o.w = rne_bf16(v.w);
    ((ushort4*)dst)[i] = o;
}

// ---------------- main GEMM+LSE (bf16 operands, global_load_lds) ----------------

__global__ __launch_bounds__(256)
void gemm_lse_bf16(const unsigned short* __restrict__ Hb, const unsigned short* __restrict__ Wb,
                   float* __restrict__ partials) {
    __shared__ unsigned short As[BM][BK];   // 8 KB, unpadded (global_load_lds layout)
    __shared__ unsigned short Bs[BN][BK];   // 8 KB

    // ntile-major: resident blocks share few W tiles -> W read ~once from HBM
    const int bid   = blockIdx.x;
    const int mtile = bid & (MTILES - 1);
    const int ntile = bid >> 6;
    const int m0 = mtile * BM;
    const int n0 = ntile * BN;

    const int tid  = threadIdx.x;
    const int lane = tid & 63;
    const int w    = tid >> 6;
    const int wm   = (w >> 1) * 64;
    const int wn   = (w & 1)  * 64;
    const int q    = lane >> 4;
    const int c    = lane & 15;

    // staging: wave w covers rows [w*32, w*32+32), 2 calls x (16 rows = 1024 B) per matrix
    // lane l -> row = base + (l>>2), k-elems = (l&3)*8
    const int srow = w * 32 + (lane >> 2);
    const int skel = (lane & 3) * 8;
    const unsigned short* gA = Hb + (size_t)(m0 + srow) * D_MODEL + skel;
    const unsigned short* gB = Wb + (size_t)(n0 + srow) * D_MODEL + skel;
    unsigned short* lA0 = &As[w * 32][0];
    unsigned short* lA1 = &As[w * 32 + 16][0];
    unsigned short* lB0 = &Bs[w * 32][0];
    unsigned short* lB1 = &Bs[w * 32 + 16][0];

    f32x4 acc[4][4];
    const f32x4 zero = {0.f, 0.f, 0.f, 0.f};
    #pragma unroll
    for (int i = 0; i < 4; ++i)
        #pragma unroll
        for (int j = 0; j < 4; ++j) acc[i][j] = zero;

    for (int kt = 0; kt < D_MODEL / BK; ++kt) {
        const int k0 = kt * BK;
        g2l16(gA + k0,                 lA0);
        g2l16(gA + k0 + 16 * D_MODEL,  lA1);
        g2l16(gB + k0,                 lB0);
        g2l16(gB + k0 + 16 * D_MODEL,  lB1);
        __syncthreads();   // drains vmcnt -> LDS populated for all waves

        frag8 af[4], bf[4];
        #pragma unroll
        for (int t = 0; t < 4; ++t)
            af[t] = *(const frag8*)&As[wm + t * 16 + c][q * 8];
        #pragma unroll
        for (int t = 0; t < 4; ++t)
            bf[t] = *(const frag8*)&Bs[wn + t * 16 + c][q * 8];

        #pragma unroll
        for (int tm = 0; tm < 4; ++tm)
            #pragma unroll
            for (int tn = 0; tn < 4; ++tn)
                acc[tm][tn] = __builtin_amdgcn_mfma_f32_16x16x32_bf16(
                    af[tm], bf[tn], acc[tm][tn], 0, 0, 0);
        __syncthreads();   // all ds_reads done before next iter's loads land
    }

    // epilogue: per-row max & sum(exp) over this wave's 64 columns
    const int chunk = ntile * 2 + (w & 1);
    #pragma unroll
    for (int tm = 0; tm < 4; ++tm) {
        #pragma unroll
        for (int r = 0; r < 4; ++r) {
            float v0 = acc[tm][0][r], v1 = acc[tm][1][r];
            float v2 = acc[tm][2][r], v3 = acc[tm][3][r];
            float mx = fmaxf(fmaxf(v0, v1), fmaxf(v2, v3));
            #pragma unroll
            for (int mask = 1; mask <= 8; mask <<= 1)
                mx = fmaxf(mx, __shfl_xor(mx, mask, 64));
            float sm = __expf(v0 - mx) + __expf(v1 - mx)
                     + __expf(v2 - mx) + __expf(v3 - mx);
            #pragma unroll
            for (int mask = 1; mask <= 8; mask <<= 1)
                sm += __shfl_xor(sm, mask, 64);
            if (c == 0) {
                int row_g = m0 + wm + tm * 16 + q * 4 + r;
                float* p = partials + ((size_t)row_g * NCHUNK + chunk) * 2;
                p[0] = mx;
                p[1] = sm;
            }
        }
    }
}

// ---------------- fallback GEMM (R1, fp32 in-flight pack) ----------------

__global__ __launch_bounds__(256, 2)
void gemm_lse_f32(const float* __restrict__ H, const float* __restrict__ W,
                  float* __restrict__ partials) {
    __shared__ unsigned short As[BM][LDK];
    __shared__ unsigned short Bs[BN][LDK];

    const int GM = 8;
    int bid   = blockIdx.x;
    int super = bid / (GM * NTILES);
    int rem   = bid % (GM * NTILES);
    int mtile = super * GM + (rem % GM);
    int ntile = rem / GM;

    const int m0 = mtile * BM;
    const int n0 = ntile * BN;

    const int tid  = threadIdx.x;
    const int lane = tid & 63;
    const int w    = tid >> 6;
    const int wm   = (w >> 1) * 64;
    const int wn   = (w & 1)  * 64;
    const int q    = lane >> 4;
    const int c    = lane & 15;

    f32x4 acc[4][4];
    const f32x4 zero = {0.f, 0.f, 0.f, 0.f};
    #pragma unroll
    for (int i = 0; i < 4; ++i)
        #pragma unroll
        for (int j = 0; j < 4; ++j) acc[i][j] = zero;

    for (int kt = 0; kt < D_MODEL / BK; ++kt) {
        const int k0 = kt * BK;
        #pragma unroll
        for (int s = 0; s < 4; ++s) {
            int i   = tid + s * 256;
            int row = i >> 3;
            int kq  = (i & 7) << 2;

            const float4* pa = (const float4*)(H + (size_t)(m0 + row) * D_MODEL + k0 + kq);
            float4 va = *pa;
            uint2 ba = { pack_bf16(va.x, va.y), pack_bf16(va.z, va.w) };
            *(uint2*)&As[row][kq] = ba;

            const float4* pb = (const float4*)(W + (size_t)(n0 + row) * D_MODEL + k0 + kq);
            float4 vb = *pb;
            uint2 bb = { pack_bf16(vb.x, vb.y), pack_bf16(vb.z, vb.w) };
            *(uint2*)&Bs[row][kq] = bb;
        }
        __syncthreads();

        frag8 af[4], bf[4];
        #pragma unroll
        for (int t = 0; t < 4; ++t)
            af[t] = *(const frag8*)&As[wm + t * 16 + c][q * 8];
        #pragma unroll
        for (int t = 0; t < 4; ++t)
            bf[t] = *(const frag8*)&Bs[wn + t * 16 + c][q * 8];

        #pragma unroll
        for (int tm = 0; tm < 4; ++tm)
            #pragma unroll
            for (int tn = 0; tn < 4; ++tn)
                acc[tm][tn] = __builtin_amdgcn_mfma_f32_16x16x32_bf16(
                    af[tm], bf[tn], acc[tm][tn], 0, 0, 0);
        __syncthreads();
    }

    const int chunk = ntile * 2 + (w & 1);
    #pragma unroll
    for (int tm = 0; tm < 4; ++tm) {
        #pragma unroll
        for (int r = 0; r < 4; ++r) {
            float v0 = acc[tm][0][r], v1 = acc[tm][1][r];
            float v2 = acc[tm][2][r], v3 = acc[tm][3][r];
            float mx = fmaxf(fmaxf(v0, v1), fmaxf(v2, v3));
            #pragma unroll
            for (int mask = 1; mask <= 8; mask <<= 1)
                mx = fmaxf(mx, __shfl_xor(mx, mask, 64));
            float sm = __expf(v0 - mx) + __expf(v1 - mx)
                     + __expf(v2 - mx) + __expf(v3 - mx);
            #pragma unroll
            for (int mask = 1; mask <= 8; mask <<= 1)
                sm += __shfl_xor(sm, mask, 64);
            if (c == 0) {
                int row_g = m0 + wm + tm * 16 + q * 4 + r;
                float* p = partials + ((size_t)row_g * NCHUNK + chunk) * 2;
                p[0] = mx;
                p[1] = sm;
            }
        }
    }
}

// ---------------- aux kernels ----------------

__global__ void tgt_kernel(const float* __restrict__ H, const float* __restrict__ W,
                           const int* __restrict__ targets,
                           float* __restrict__ tgt_logit, float* __restrict__ accum) {
    int token = blockIdx.x;
    int tid   = threadIdx.x;
    if (token == 0 && tid == 0) { accum[0] = 0.f; accum[1] = 0.f; }

    int t  = targets[token];
    int tt = (t == -100) ? 0 : t;
    const float4* h  = (const float4*)(H + (size_t)token * D_MODEL);
    const float4* wr = (const float4*)(W + (size_t)tt * D_MODEL);
    float p = 0.f;
    for (int j = tid; j < D_MODEL / 4; j += 256) {
        float4 a = h[j], b = wr[j];
        p += a.x * b.x + a.y * b.y + a.z * b.z + a.w * b.w;
    }
    #pragma unroll
    for (int mask = 1; mask < 64; mask <<= 1)
        p += __shfl_xor(p, mask, 64);

    __shared__ float lp[4];
    int lane = tid & 63, wid = tid >> 6;
    if (lane == 0) lp[wid] = p;
    __syncthreads();
    if (tid == 0) tgt_logit[token] = lp[0] + lp[1] + lp[2] + lp[3];
}

__device__ inline void lse_merge(float& m, float& s, float om, float os) {
    if (om > m) { s = s * __expf(m - om) + os; m = om; }
    else        { s += os * __expf(om - m); }
}

__global__ void reduce_kernel(const float* __restrict__ partials,
                              const float* __restrict__ tgt_logit,
                              const int* __restrict__ targets,
                              float* __restrict__ accum) {
    int token = blockIdx.x;
    int tid   = threadIdx.x;
    float m = -INFINITY, s = 0.f;
    for (int ch = tid; ch < NCHUNK; ch += 256) {
        const float* p = partials + ((size_t)token * NCHUNK + ch) * 2;
        lse_merge(m, s, p[0], p[1]);
    }
    #pragma unroll
    for (int mask = 1; mask < 64; mask <<= 1) {
        float om = __shfl_xor(m, mask, 64);
        float os = __shfl_xor(s, mask, 64);
        lse_merge(m, s, om, os);
    }
    __shared__ float lm[4], ls[4];
    int lane = tid & 63, wid = tid >> 6;
    if (lane == 0) { lm[wid] = m; ls[wid] = s; }
    __syncthreads();
    if (tid == 0) {
        for (int i = 1; i < 4; ++i) lse_merge(m, s, lm[i], ls[i]);
        float lse = m + __logf(s);
        int t = targets[token];
        if (t != -100) {
            atomicAdd(&accum[0], lse - tgt_logit[token]);
            atomicAdd(&accum[1], 1.0f);
        }
    }
}

__global__ void final_kernel(const float* __restrict__ accum, float* __restrict__ out) {
    float L = accum[0], C = accum[1];
    out[0] = (C > 0.f) ? (L / C) : 0.f;
}

// ---------------- launch ----------------

extern "C" void kernel_launch(void* const* d_in, const int* in_sizes, int n_in,
                              void* d_out, int out_size, void* d_ws, size_t ws_size,
                              hipStream_t stream) {
    (void)in_sizes; (void)n_in; (void)out_size;
    const float* H       = (const float*)d_in[0];   // [4,2048,2048]
    const int*   targets = (const int*)d_in[1];     // [8192]
    const float* W       = (const float*)d_in[2];   // [32000,2048]
    float*       out     = (float*)d_out;

    char* ws = (char*)d_ws;
    const size_t HB_BYTES   = (size_t)NTOK  * D_MODEL * 2;       //  32 MB
    const size_t WB_BYTES   = (size_t)VOCAB * D_MODEL * 2;       // 128 MB
    const size_t PART_BYTES = (size_t)NTOK * NCHUNK * 2 * 4;     //  32 MB
    const size_t NEED = HB_BYTES + WB_BYTES + PART_BYTES + (size_t)NTOK * 4 + 64;

    if (ws_size >= NEED) {
        unsigned short* Hb = (unsigned short*)ws;
        unsigned short* Wb = (unsigned short*)(ws + HB_BYTES);
        float* partials    = (float*)(ws + HB_BYTES + WB_BYTES);
        float* tgt_logit   = (float*)(ws + HB_BYTES + WB_BYTES + PART_BYTES);
        float* accum       = tgt_logit + NTOK;

        cvt_bf16_kernel<<<(NTOK * D_MODEL / 4) / 256, 256, 0, stream>>>(H, Hb);
        cvt_bf16_kernel<<<(VOCAB * D_MODEL / 4) / 256, 256, 0, stream>>>(W, Wb);
        tgt_kernel<<<NTOK, 256, 0, stream>>>(H, W, targets, tgt_logit, accum);
        gemm_lse_bf16<<<MTILES * NTILES, 256, 0, stream>>>(Hb, Wb, partials);
        reduce_kernel<<<NTOK, 256, 0, stream>>>(partials, tgt_logit, targets, accum);
        final_kernel<<<1, 1, 0, stream>>>(accum, out);
    } else {
        float* partials  = (float*)ws;
        float* tgt_logit = (float*)(ws + PART_BYTES);
        float* accum     = tgt_logit + NTOK;

        gemm_lse_f32<<<MTILES * NTILES, 256, 0, stream>>>(H, W, partials);
        tgt_kernel<<<NTOK, 256, 0, stream>>>(H, W, targets, tgt_logit, accum);
        reduce_kernel<<<NTOK, 256, 0, stream>>>(partials, tgt_logit, targets, accum);
        final_kernel<<<1, 1, 0, stream>>>(accum, out);
    }
}